// Round 1
// 172.635 us; speedup vs baseline: 1.0072x; 1.0072x over previous
//
#include <hip/hip_runtime.h>
#include <stdint.h>

// DataEmbedder: fused categorical embedding gather + numeric passthrough concat.
// dataset [R=262144, 12] fp32: cols 0-3 = raw category ids (as floats),
// cols 4-11 = numeric features. Output [R, 128] fp32:
//   [emb0(32) | emb1(64) | emb2(16) | emb3(8) | numeric(8)]
//
// R6: block-cooperative, 64 rows per 256-thread block.
//  Phase 1: stage dataset tile (64x12 f32 = 3KB) into LDS via 192 coalesced
//           nontemporal f4 loads (dataset is streamed once; NT avoids evicting
//           the 1.4MB emb tables from L2).
//  Phase 2: compute the 64x4 mapped ids ONCE (thread t -> row t>>2, col t&3):
//           LDS raw -> lut gather -> LDS ids. Dedupes the old per-lane
//           id+lut dependent chains (~15x fewer lut chains).
//  Phase 3: thread = (g = t>>5 row-group, k = t&31 chunk). Segment descriptor
//           is a function of k only -> computed ONCE per 8 rows (vs per 2 in
//           R5). 8 independent chains: LDS id read -> f4 gather -> f4 store,
//           fully unrolled so 8 gathers are in flight. Chain no longer starts
//           with an HBM-latency scalar id load.
//  Stores: store i, lanes 0-31 -> row (i*8+g0) chunks 0-31 (512B run), lanes
//  32-63 -> row (i*8+g0+1) (adjacent 512B) => 1KB contiguous per store instr.
//  Coherent stores (NT stores lose races with the harness d_out re-poison --
//  R3 post-mortem).

typedef float f4 __attribute__((ext_vector_type(4)));

#define RPB 64   // rows per block (nrows = 262144 is a multiple of 64)

__global__ __launch_bounds__(256) void data_embedder_kernel(
    const float* __restrict__ ds,
    const float* __restrict__ e0, const int* __restrict__ l0,
    const float* __restrict__ e1, const int* __restrict__ l1,
    const float* __restrict__ e2, const int* __restrict__ l2,
    const float* __restrict__ e3, const int* __restrict__ l3,
    float* __restrict__ out, int nrows)
{
    __shared__ __attribute__((aligned(16))) float sds[RPB * 12]; // 3KB tile
    __shared__ int sid[RPB * 4];                                 // 1KB mapped ids

    int t = threadIdx.x;
    int row0 = blockIdx.x * RPB;

    // ---- Phase 1: coalesced tile load (192 x 16B = 3KB) ----
    if (t < RPB * 12 / 4) {
        const f4* src = (const f4*)(ds + (size_t)row0 * 12) + t;  // row0*48B is 16B-aligned (48=3*16)
        f4 v = __builtin_nontemporal_load(src);
        *(f4*)(sds + t * 4) = v;
    }
    __syncthreads();

    // ---- Phase 2: 64 rows x 4 cols mapped ids, one lookup per thread ----
    {
        int r = t >> 2, c = t & 3;
        int raw = (int)sds[r * 12 + c];
        const int* lut = c == 0 ? l0 : c == 1 ? l1 : c == 2 ? l2 : l3;
        sid[t] = lut[raw];                    // t == r*4 + c
    }
    __syncthreads();

    // ---- Phase 3: 8 rows per thread, descriptor hoisted ----
    int k = t & 31;          // output 16B chunk within a row
    int g = t >> 5;          // row group 0..7

    //   k in [0,8)   emb0: stride 32, col 0
    //   k in [8,24)  emb1: stride 64, col 1
    //   k in [24,28) emb2: stride 16, col 2
    //   k in [28,30) emb3: stride  8, col 3
    //   k in [30,32) numeric: base ds+4, stride 12, id = global row
    bool s0 = k < 8, s1 = k < 24, s2 = k < 28, s3 = k < 30;
    const float* base = s0 ? e0 : s1 ? e1 : s2 ? e2 : s3 ? e3 : (ds + 4);
    int stride = s0 ? 32 : s1 ? 64 : s2 ? 16 : s3 ? 8 : 12;
    int off    = (s0 ? k : s1 ? (k - 8) : s2 ? (k - 24) : s3 ? (k - 28) : (k - 30)) * 4;
    int col    = s0 ? 0 : s1 ? 1 : s2 ? 2 : 3;   // k>=30: col 3 (dummy LDS read, safe)
    const float* bo = base + off;

    float* orow = out + (size_t)row0 * 128 + k * 4;

    // 8 independent chains: LDS id -> gather -> store. Full static unroll
    // (arrays stay in registers -- all indices compile-time).
    f4 v[8];
    #pragma unroll
    for (int i = 0; i < 8; ++i) {
        int r  = i * 8 + g;
        int m  = sid[r * 4 + col];            // broadcast LDS read (lanes share r)
        int id = s3 ? m : (row0 + r);         // numeric chunks index global ds rows
        v[i] = *(const f4*)(bo + (size_t)id * stride);
    }
    #pragma unroll
    for (int i = 0; i < 8; ++i) {
        int r = i * 8 + g;
        *(f4*)(orow + (size_t)r * 128) = v[i];
    }
}

extern "C" void kernel_launch(void* const* d_in, const int* in_sizes, int n_in,
                              void* d_out, int out_size, void* d_ws, size_t ws_size,
                              hipStream_t stream) {
    // setup_inputs() dict order: dataset, emb0, lut0, emb1, lut1, emb2, lut2, emb3, lut3
    const float* ds = (const float*)d_in[0];
    const float* e0 = (const float*)d_in[1];
    const int*   l0 = (const int*)  d_in[2];
    const float* e1 = (const float*)d_in[3];
    const int*   l1 = (const int*)  d_in[4];
    const float* e2 = (const float*)d_in[5];
    const int*   l2 = (const int*)  d_in[6];
    const float* e3 = (const float*)d_in[7];
    const int*   l3 = (const int*)  d_in[8];
    float* out = (float*)d_out;

    int nrows = in_sizes[0] / 12;             // 64 * 4096 = 262144 (multiple of 64)
    int grid  = nrows / RPB;                  // 4096 blocks x 256 threads

    data_embedder_kernel<<<grid, 256, 0, stream>>>(
        ds, e0, l0, e1, l1, e2, l2, e3, l3, out, nrows);
}